// Round 1
// baseline (2773.916 us; speedup 1.0000x reference)
//
#include <hip/hip_runtime.h>

#define NPG 1024
#define BGR 256
#define NN  (NPG*BGR)        // 262144 nodes
#define EE  (16*NN)          // 4194304 edges
#define HH  128

#define OFF_MUI ((size_t)NN*64)
#define OFF_LVI ((size_t)NN*64*2)
#define OFF_ZA  ((size_t)NN*64*3)
#define OFF_MUA (OFF_ZA + (size_t)BGR*64)
#define OFF_LVA (OFF_ZA + (size_t)BGR*64*2)

__device__ __forceinline__ float bflo(unsigned u){ return __uint_as_float(u<<16); }
__device__ __forceinline__ float bfhi(unsigned u){ return __uint_as_float(u & 0xffff0000u); }
__device__ __forceinline__ float bfs(unsigned short v){ return __uint_as_float(((unsigned)v)<<16); }
__device__ __forceinline__ unsigned short f2bf(float f){
  unsigned x = __float_as_uint(f);
  x += 0x7fffu + ((x>>16)&1u);
  return (unsigned short)(x>>16);
}
__device__ __forceinline__ unsigned packbf(float a, float b){
  return (unsigned)f2bf(a) | ((unsigned)f2bf(b)<<16);
}

// ---------------- CSR build ----------------
__global__ __launch_bounds__(256) void count_k(const int* __restrict__ dst, int* __restrict__ cnt){
  int e = blockIdx.x*256 + threadIdx.x;
  atomicAdd(&cnt[dst[e]], 1);
}

__global__ __launch_bounds__(256) void dinv_k(const int* __restrict__ cnt, float* __restrict__ dinv){
  int n = blockIdx.x*256 + threadIdx.x;
  dinv[n] = rsqrtf((float)cnt[n] + 1.0f);
}

__global__ __launch_bounds__(256) void reduce256_k(const int* __restrict__ cnt, int* __restrict__ bsum){
  __shared__ int red[256];
  int t = threadIdx.x;
  red[t] = cnt[blockIdx.x*256 + t];
  __syncthreads();
  for (int off=128; off>0; off>>=1){ if (t<off) red[t] += red[t+off]; __syncthreads(); }
  if (t==0) bsum[blockIdx.x] = red[0];
}

__global__ __launch_bounds__(1024) void scan1024_k(int* __restrict__ bsum){
  __shared__ int tmp[1024];
  int t = threadIdx.x;
  int v = bsum[t];
  tmp[t] = v; __syncthreads();
  for (int off=1; off<1024; off<<=1){
    int add = (t>=off) ? tmp[t-off] : 0;
    __syncthreads();
    tmp[t] += add;
    __syncthreads();
  }
  bsum[t] = tmp[t] - v;   // exclusive prefix
}

__global__ __launch_bounds__(256) void scanfinal_k(const int* __restrict__ cnt, const int* __restrict__ boff,
                                                   int* __restrict__ rowptr, int* __restrict__ fill){
  __shared__ int tmp[256];
  int t = threadIdx.x, gid = blockIdx.x*256 + t;
  int v = cnt[gid];
  tmp[t] = v; __syncthreads();
  for (int off=1; off<256; off<<=1){
    int add = (t>=off) ? tmp[t-off] : 0;
    __syncthreads();
    tmp[t] += add;
    __syncthreads();
  }
  int excl = boff[blockIdx.x] + tmp[t] - v;
  rowptr[gid] = excl; fill[gid] = excl;
  if (gid==0) rowptr[NN] = EE;
}

__global__ __launch_bounds__(256) void fill_k(const int* __restrict__ src, const int* __restrict__ dst,
                                              int* __restrict__ fill, int* __restrict__ colv){
  int e = blockIdx.x*256 + threadIdx.x;
  int d = dst[e];
  int pos = atomicAdd(&fill[d], 1);
  colv[pos] = src[e];
}

// ---------------- tiled GEMM: C[M x BN] = A'[M x 128] @ W[128 x BN] (+bias) ----------------
// AMODE 0: A fp32 raw; AMODE 1: A bf16 + per-col affine + ReLU. OUTBF: bf16 out else fp32.
template<int BN, int AMODE, int OUTBF, int HASB>
__global__ __launch_bounds__(256) void gemm_k(
    const void* __restrict__ Ap, const float* __restrict__ scale, const float* __restrict__ shift,
    const float* __restrict__ W, const float* __restrict__ bias, void* __restrict__ Cp)
{
  constexpr int TC  = BN/8;      // col groups (thread has 4+4 cols split by HALF)
  constexpr int TR  = 256/TC;
  constexpr int RPT = 64/TR;
  constexpr int HALF = BN/2;
  __shared__ float Al[64][132];
  __shared__ float Wl[16][BN];
  const int tid = threadIdx.x;
  const int row0 = blockIdx.x*64;

  if constexpr (AMODE==1){
    const unsigned* A2 = (const unsigned*)Ap;
    #pragma unroll
    for (int i=0;i<16;i++){
      int idx = tid + i*256;
      int r = idx>>6, cp = idx&63;
      unsigned u = A2[(size_t)(row0+r)*64 + cp];
      int c = cp*2;
      Al[r][c]   = fmaxf(fmaf(bflo(u), scale[c],   shift[c]),   0.f);
      Al[r][c+1] = fmaxf(fmaf(bfhi(u), scale[c+1], shift[c+1]), 0.f);
    }
  } else {
    const float2* A2 = (const float2*)Ap;
    #pragma unroll
    for (int i=0;i<16;i++){
      int idx = tid + i*256;
      int r = idx>>6, cp = idx&63;
      float2 v = A2[(size_t)(row0+r)*64 + cp];
      Al[r][cp*2] = v.x; Al[r][cp*2+1] = v.y;
    }
  }

  const int cg = tid % TC, rg = tid / TC;
  const int col0 = cg*4;         // cols [col0, col0+4) and [col0+HALF, col0+HALF+4)
  const int rb = rg*RPT;
  float acc[RPT][8];
  #pragma unroll
  for (int i=0;i<RPT;i++){
    #pragma unroll
    for (int j=0;j<8;j++){
      if constexpr (HASB) acc[i][j] = bias[(j<4) ? (col0+j) : (col0+HALF+j-4)];
      else acc[i][j] = 0.f;
    }
  }

  for (int kc=0; kc<128; kc+=16){
    __syncthreads();
    #pragma unroll
    for (int i=0;i<(16*BN)/256;i++){
      int idx = tid + i*256;
      Wl[idx/BN][idx%BN] = W[(size_t)(kc + idx/BN)*BN + (idx%BN)];
    }
    __syncthreads();
    #pragma unroll
    for (int k=0;k<16;k++){
      float a[RPT];
      #pragma unroll
      for (int i=0;i<RPT;i++) a[i] = Al[rb+i][kc+k];
      float4 w0 = *(const float4*)&Wl[k][col0];
      float4 w1 = *(const float4*)&Wl[k][col0+HALF];
      #pragma unroll
      for (int i=0;i<RPT;i++){
        acc[i][0] = fmaf(a[i], w0.x, acc[i][0]);
        acc[i][1] = fmaf(a[i], w0.y, acc[i][1]);
        acc[i][2] = fmaf(a[i], w0.z, acc[i][2]);
        acc[i][3] = fmaf(a[i], w0.w, acc[i][3]);
        acc[i][4] = fmaf(a[i], w1.x, acc[i][4]);
        acc[i][5] = fmaf(a[i], w1.y, acc[i][5]);
        acc[i][6] = fmaf(a[i], w1.z, acc[i][6]);
        acc[i][7] = fmaf(a[i], w1.w, acc[i][7]);
      }
    }
  }

  if constexpr (OUTBF){
    unsigned short* C = (unsigned short*)Cp;
    #pragma unroll
    for (int i=0;i<RPT;i++){
      int row = row0 + rb + i;
      uint2 p0; p0.x = packbf(acc[i][0], acc[i][1]); p0.y = packbf(acc[i][2], acc[i][3]);
      uint2 p1; p1.x = packbf(acc[i][4], acc[i][5]); p1.y = packbf(acc[i][6], acc[i][7]);
      *(uint2*)&C[(size_t)row*BN + col0] = p0;
      *(uint2*)&C[(size_t)row*BN + col0 + HALF] = p1;
    }
  } else {
    float* C = (float*)Cp;
    #pragma unroll
    for (int i=0;i<RPT;i++){
      int row = row0 + rb + i;
      float4 f0 = {acc[i][0],acc[i][1],acc[i][2],acc[i][3]};
      float4 f1 = {acc[i][4],acc[i][5],acc[i][6],acc[i][7]};
      *(float4*)&C[(size_t)row*BN + col0] = f0;
      *(float4*)&C[(size_t)row*BN + col0 + HALF] = f1;
    }
  }
}

// ---------------- GCN aggregation: one wave per dst node ----------------
__global__ __launch_bounds__(256) void agg_k(const unsigned* __restrict__ xw, const int* __restrict__ rowptr,
    const int* __restrict__ colv, const float* __restrict__ dinv, const float* __restrict__ bias,
    unsigned* __restrict__ outb)
{
  int node = blockIdx.x*4 + (threadIdx.x>>6);
  int lane = threadIdx.x & 63;
  int beg = rowptr[node], end = rowptr[node+1];
  float dn = dinv[node];
  unsigned su = xw[(size_t)node*64 + lane];
  float a0 = bflo(su)*dn, a1 = bfhi(su)*dn;   // self-loop: xw[n]*dinv[n]
  int i = beg;
  for (; i+2 <= end; i += 2){
    int s0 = colv[i], s1 = colv[i+1];
    float d0 = dinv[s0], d1 = dinv[s1];
    unsigned u0 = xw[(size_t)s0*64 + lane];
    unsigned u1 = xw[(size_t)s1*64 + lane];
    a0 = fmaf(bflo(u0), d0, a0); a1 = fmaf(bfhi(u0), d0, a1);
    a0 = fmaf(bflo(u1), d1, a0); a1 = fmaf(bfhi(u1), d1, a1);
  }
  if (i < end){
    int s0 = colv[i]; float d0 = dinv[s0];
    unsigned u0 = xw[(size_t)s0*64 + lane];
    a0 = fmaf(bflo(u0), d0, a0); a1 = fmaf(bfhi(u0), d0, a1);
  }
  int c = lane*2;
  a0 = fmaf(a0, dn, bias[c]);     // * dinv[n] outer factor + bias
  a1 = fmaf(a1, dn, bias[c+1]);
  outb[(size_t)node*64 + lane] = packbf(a0, a1);
}

// ---------------- BN stats (sum, sumsq per column) ----------------
__global__ __launch_bounds__(256) void stats_k(const unsigned short* __restrict__ a,
                                               float* __restrict__ gsum, float* __restrict__ gss)
{
  int t = threadIdx.x;
  int c = t & 127, h = t >> 7;
  size_t r0 = (size_t)blockIdx.x * 256;
  float s = 0.f, ss = 0.f;
  for (int r = h; r < 256; r += 2){
    float v = bfs(a[(r0 + r)*128 + c]);
    s += v; ss = fmaf(v, v, ss);
  }
  __shared__ float red[256];
  red[t] = s; __syncthreads();
  if (t < 128) atomicAdd(&gsum[c], red[t] + red[t+128]);
  __syncthreads();
  red[t] = ss; __syncthreads();
  if (t < 128) atomicAdd(&gss[c], red[t] + red[t+128]);
}

__global__ void fin_k(const float* __restrict__ gsum, const float* __restrict__ gss,
                      const float* __restrict__ g, const float* __restrict__ be,
                      float* __restrict__ scale, float* __restrict__ shift)
{
  int c = threadIdx.x;
  float mean = gsum[c] * (1.0f/NN);
  float var  = gss[c]  * (1.0f/NN) - mean*mean;
  float rs = rsqrtf(var + 1e-5f);
  float sc = g[c]*rs;
  scale[c] = sc;
  shift[c] = be[c] - mean*sc;
}

// ---------------- phi = h1@phi1_w + phi1_b + h2@phi2_w ----------------
__global__ __launch_bounds__(256) void phi_k(const unsigned* __restrict__ a1, const float* __restrict__ sc1, const float* __restrict__ sh1,
    const unsigned* __restrict__ a2, const float* __restrict__ sc2, const float* __restrict__ sh2,
    const float* __restrict__ p1w, const float* __restrict__ p1b, const float* __restrict__ p2w,
    float* __restrict__ phi)
{
  int node = blockIdx.x*4 + (threadIdx.x>>6);
  int lane = threadIdx.x & 63;
  int c = lane*2;
  unsigned u1 = a1[(size_t)node*64+lane], u2 = a2[(size_t)node*64+lane];
  float h10 = fmaxf(fmaf(bflo(u1), sc1[c],   sh1[c]),   0.f);
  float h11 = fmaxf(fmaf(bfhi(u1), sc1[c+1], sh1[c+1]), 0.f);
  float h20 = fmaxf(fmaf(bflo(u2), sc2[c],   sh2[c]),   0.f);
  float h21 = fmaxf(fmaf(bfhi(u2), sc2[c+1], sh2[c+1]), 0.f);
  float acc = h10*p1w[c] + h11*p1w[c+1] + h20*p2w[c] + h21*p2w[c+1];
  #pragma unroll
  for (int off=32; off>0; off>>=1) acc += __shfl_xor(acc, off);
  if (lane==0) phi[node] = acc + p1b[0];
}

// ---------------- per-graph softmax + h_graph ----------------
__global__ __launch_bounds__(256) void attn_k(const float* __restrict__ phi, const unsigned short* __restrict__ a3,
    const float* __restrict__ sc3, const float* __restrict__ sh3, float* __restrict__ hgraph)
{
  int b = blockIdx.x, t = threadIdx.x;
  __shared__ float at[1024];
  __shared__ float red[256];
  const float* ph = phi + (size_t)b*1024;
  float m = -1e30f;
  for (int i=t;i<1024;i+=256) m = fmaxf(m, ph[i]);
  red[t] = m; __syncthreads();
  for (int off=128; off>0; off>>=1){ if (t<off) red[t] = fmaxf(red[t], red[t+off]); __syncthreads(); }
  m = red[0]; __syncthreads();
  float s = 0.f;
  for (int i=t;i<1024;i+=256){ float e = expf(ph[i]-m); at[i] = e; s += e; }
  red[t] = s; __syncthreads();
  for (int off=128; off>0; off>>=1){ if (t<off) red[t] += red[t+off]; __syncthreads(); }
  float inv = 1.0f/red[0];
  __syncthreads();
  int c = t & 127, h = t >> 7;
  float acc = 0.f;
  const unsigned short* base = a3 + (size_t)b*1024*128;
  float sc = sc3[c], sh = sh3[c];
  for (int p=h; p<1024; p+=2){
    float v = bfs(base[(size_t)p*128 + c]);
    float hv = fmaxf(fmaf(v, sc, sh), 0.f);
    acc = fmaf(hv, at[p], acc);
  }
  red[t] = acc; __syncthreads();
  if (t < 128) hgraph[(size_t)b*128 + t] = (red[t] + red[t+128]) * inv;
}

// ---------------- graph latent head ----------------
__global__ __launch_bounds__(64) void za_k(const float* __restrict__ hg,
   const float* __restrict__ muw, const float* __restrict__ mub,
   const float* __restrict__ lvw, const float* __restrict__ lvb,
   const float* __restrict__ epsA, float* __restrict__ out)
{
  int b = blockIdx.x, j = threadIdx.x;
  __shared__ float h[128];
  h[j] = hg[(size_t)b*128 + j]; h[j+64] = hg[(size_t)b*128 + 64 + j];
  __syncthreads();
  float mu = mub[j], lv = lvb[j];
  #pragma unroll 8
  for (int c=0;c<128;c++){
    mu = fmaf(h[c], muw[c*64+j], mu);
    lv = fmaf(h[c], lvw[c*64+j], lv);
  }
  float z = mu + epsA[(size_t)b*64+j]*expf(0.5f*lv);
  size_t o = (size_t)b*64 + j;
  out[OFF_ZA  + o] = z;
  out[OFF_MUA + o] = mu;
  out[OFF_LVA + o] = lv;
}

// ---------------- zt: s += z_A[b] @ WA[p], one block per node position p ----------------
__global__ __launch_bounds__(256) void zt_k(const float* __restrict__ zA, const float* __restrict__ WA,
                                            float* __restrict__ s)
{
  __shared__ float wa[4096];
  int p = blockIdx.x, t = threadIdx.x;
  #pragma unroll
  for (int i=0;i<16;i++){ int idx = t + i*256; wa[idx] = WA[(size_t)p*4096 + idx]; }
  __syncthreads();
  int f = t & 63, bg = t >> 6;
  for (int b = bg; b < 256; b += 4){
    const float* za = zA + (size_t)b*64;
    float acc = 0.f;
    #pragma unroll 8
    for (int g=0; g<64; g++) acc = fmaf(za[g], wa[g*64+f], acc);
    size_t idx = ((size_t)b*1024 + p)*64 + f;
    s[idx] += acc;
  }
}

// ---------------- node head: mu_i, logvar_i, z_i ----------------
__global__ __launch_bounds__(256) void out_k(const float* __restrict__ s,
    const float* __restrict__ muw, const float* __restrict__ mub,
    const float* __restrict__ lvw, const float* __restrict__ lvb,
    const float* __restrict__ eps, float* __restrict__ out)
{
  __shared__ float wmu[4096];
  __shared__ float wlv[4096];
  __shared__ float sl[4096];
  int t = threadIdx.x;
  size_t base = (size_t)blockIdx.x * 64;
  #pragma unroll
  for (int i=0;i<16;i++){
    int idx = t + i*256;
    wmu[idx] = muw[idx]; wlv[idx] = lvw[idx];
    sl[idx] = s[base*64 + idx];
  }
  __syncthreads();
  int f = t & 63, ng = t >> 6;
  float mb = mub[f], lb = lvb[f];
  for (int nl = ng; nl < 64; nl += 4){
    size_t node = base + nl;
    float mu = mb, lv = lb;
    const float* srow = &sl[nl*64];
    #pragma unroll 16
    for (int k=0;k<64;k++){
      float sv = srow[k];
      mu = fmaf(sv, wmu[k*64+f], mu);
      lv = fmaf(sv, wlv[k*64+f], lv);
    }
    float e = eps[node*64 + f];
    float zi = mu + e*expf(0.5f*lv);
    size_t o = node*64 + f;
    out[o] = zi;
    out[OFF_MUI + o] = mu;
    out[OFF_LVI + o] = lv;
  }
}

extern "C" void kernel_launch(void* const* d_in, const int* in_sizes, int n_in,
                              void* d_out, int out_size, void* d_ws, size_t ws_size,
                              hipStream_t stream)
{
  (void)in_sizes; (void)n_in; (void)out_size; (void)ws_size;
  const float* x    = (const float*)d_in[0];
  const float* epsA = (const float*)d_in[1];
  const float* epsI = (const float*)d_in[2];
  const float* W1 = (const float*)d_in[3];
  const float* b1 = (const float*)d_in[4];
  const float* W2 = (const float*)d_in[5];
  const float* b2 = (const float*)d_in[6];
  const float* W3 = (const float*)d_in[7];
  const float* b3 = (const float*)d_in[8];
  const float* g1 = (const float*)d_in[9];
  const float* be1= (const float*)d_in[10];
  const float* g2 = (const float*)d_in[11];
  const float* be2= (const float*)d_in[12];
  const float* g3 = (const float*)d_in[13];
  const float* be3= (const float*)d_in[14];
  const float* p1w= (const float*)d_in[15];
  const float* p1b= (const float*)d_in[16];
  const float* p2w= (const float*)d_in[17];
  const float* muAw=(const float*)d_in[18];
  const float* muAb=(const float*)d_in[19];
  const float* lvAw=(const float*)d_in[20];
  const float* lvAb=(const float*)d_in[21];
  const float* Whw= (const float*)d_in[22];
  const float* Whb= (const float*)d_in[23];
  const float* WAp= (const float*)d_in[24];
  const float* muiw=(const float*)d_in[25];
  const float* muib=(const float*)d_in[26];
  const float* lviw=(const float*)d_in[27];
  const float* lvib=(const float*)d_in[28];
  const int* edge = (const int*)d_in[29];
  const int* srcp = edge;
  const int* dstp = edge + EE;

  // workspace layout (~224 MB)
  char* w = (char*)d_ws;
  size_t o = 0;
  auto alloc = [&](size_t bytes)->void*{ void* p = w + o; o += (bytes + 255) & ~(size_t)255; return p; };
  void* bufX = alloc((size_t)NN*128*2);   // bf16 xw; later reused as fp32 s[N][64] (same byte size)
  void* buf1 = alloc((size_t)NN*128*2);   // agg1 (bf16), later agg3
  void* buf2 = alloc((size_t)NN*128*2);   // agg2 (bf16)
  int*   colv  = (int*)alloc((size_t)EE*4);
  int*   cnt   = (int*)alloc((size_t)NN*4);
  int*   rowptr= (int*)alloc((size_t)(NN+1)*4);
  int*   fill  = (int*)alloc((size_t)NN*4);
  float* dinv  = (float*)alloc((size_t)NN*4);
  float* phi   = (float*)alloc((size_t)NN*4);
  int*   bsum  = (int*)alloc(1024*4);
  float* stats = (float*)alloc(768*4);    // sum1,ss1,sum2,ss2,sum3,ss3 (128 each)
  float* aff   = (float*)alloc(768*4);    // sc1,sh1,sc2,sh2,sc3,sh3
  float* hgraph= (float*)alloc((size_t)BGR*128*4);
  float* sc1 = aff, *sh1 = aff+128, *sc2 = aff+256, *sh2 = aff+384, *sc3 = aff+512, *sh3 = aff+640;

  hipMemsetAsync(cnt, 0, (size_t)NN*4, stream);
  hipMemsetAsync(stats, 0, 768*4, stream);

  // CSR build
  count_k<<<EE/256,256,0,stream>>>(dstp, cnt);
  dinv_k<<<NN/256,256,0,stream>>>(cnt, dinv);
  reduce256_k<<<NN/256,256,0,stream>>>(cnt, bsum);
  scan1024_k<<<1,1024,0,stream>>>(bsum);
  scanfinal_k<<<NN/256,256,0,stream>>>(cnt, bsum, rowptr, fill);
  fill_k<<<EE/256,256,0,stream>>>(srcp, dstp, fill, colv);

  float* out = (float*)d_out;

  // layer 1
  gemm_k<128,0,1,0><<<NN/64,256,0,stream>>>(x, nullptr, nullptr, W1, nullptr, bufX);
  agg_k<<<NN/4,256,0,stream>>>((const unsigned*)bufX, rowptr, colv, dinv, b1, (unsigned*)buf1);
  stats_k<<<NN/256,256,0,stream>>>((const unsigned short*)buf1, stats+0, stats+128);
  fin_k<<<1,128,0,stream>>>(stats+0, stats+128, g1, be1, sc1, sh1);
  // layer 2
  gemm_k<128,1,1,0><<<NN/64,256,0,stream>>>(buf1, sc1, sh1, W2, nullptr, bufX);
  agg_k<<<NN/4,256,0,stream>>>((const unsigned*)bufX, rowptr, colv, dinv, b2, (unsigned*)buf2);
  stats_k<<<NN/256,256,0,stream>>>((const unsigned short*)buf2, stats+256, stats+384);
  fin_k<<<1,128,0,stream>>>(stats+256, stats+384, g2, be2, sc2, sh2);
  // phi (needs h1,h2) before buf1 is reused for agg3
  phi_k<<<NN/4,256,0,stream>>>((const unsigned*)buf1, sc1, sh1, (const unsigned*)buf2, sc2, sh2,
                               p1w, p1b, p2w, phi);
  // layer 3
  gemm_k<128,1,1,0><<<NN/64,256,0,stream>>>(buf2, sc2, sh2, W3, nullptr, bufX);
  agg_k<<<NN/4,256,0,stream>>>((const unsigned*)bufX, rowptr, colv, dinv, b3, (unsigned*)buf1);
  stats_k<<<NN/256,256,0,stream>>>((const unsigned short*)buf1, stats+512, stats+640);
  fin_k<<<1,128,0,stream>>>(stats+512, stats+640, g3, be3, sc3, sh3);
  // attention pooling + graph latent
  attn_k<<<BGR,256,0,stream>>>(phi, (const unsigned short*)buf1, sc3, sh3, hgraph);
  za_k<<<BGR,64,0,stream>>>(hgraph, muAw, muAb, lvAw, lvAb, epsA, out);
  // node head: s = h3 @ Wh_w + Wh_b  (fp32, into bufX)
  gemm_k<64,1,0,1><<<NN/64,256,0,stream>>>(buf1, sc3, sh3, Whw, Whb, bufX);
  zt_k<<<NPG,256,0,stream>>>(out + OFF_ZA, WAp, (float*)bufX);
  out_k<<<NN/64,256,0,stream>>>((const float*)bufX, muiw, muib, lviw, lvib, epsI, out);
}

// Round 2
// 2166.561 us; speedup vs baseline: 1.2803x; 1.2803x over previous
//
#include <hip/hip_runtime.h>

#define NPG 1024
#define BGR 256
#define NN  (NPG*BGR)        // 262144 nodes
#define EE  (16*NN)          // 4194304 edges
#define HH  128

#define OFF_MUI ((size_t)NN*64)
#define OFF_LVI ((size_t)NN*64*2)
#define OFF_ZA  ((size_t)NN*64*3)
#define OFF_MUA (OFF_ZA + (size_t)BGR*64)
#define OFF_LVA (OFF_ZA + (size_t)BGR*64*2)

typedef __attribute__((ext_vector_type(8))) short short8;
typedef __attribute__((ext_vector_type(4))) float f32x4;

__device__ __forceinline__ float bflo(unsigned u){ return __uint_as_float(u<<16); }
__device__ __forceinline__ float bfhi(unsigned u){ return __uint_as_float(u & 0xffff0000u); }
__device__ __forceinline__ float bfs(unsigned short v){ return __uint_as_float(((unsigned)v)<<16); }
__device__ __forceinline__ unsigned short f2bf(float f){
  unsigned x = __float_as_uint(f);
  x += 0x7fffu + ((x>>16)&1u);
  return (unsigned short)(x>>16);
}
__device__ __forceinline__ unsigned packbf(float a, float b){
  return (unsigned)f2bf(a) | ((unsigned)f2bf(b)<<16);
}

// ---------------- CSR build ----------------
__global__ __launch_bounds__(256) void count_k(const int* __restrict__ dst, int* __restrict__ cnt){
  int e = blockIdx.x*256 + threadIdx.x;
  atomicAdd(&cnt[dst[e]], 1);
}

__global__ __launch_bounds__(256) void dinv_k(const int* __restrict__ cnt, float* __restrict__ dinv){
  int n = blockIdx.x*256 + threadIdx.x;
  dinv[n] = rsqrtf((float)cnt[n] + 1.0f);
}

__global__ __launch_bounds__(256) void reduce256_k(const int* __restrict__ cnt, int* __restrict__ bsum){
  __shared__ int red[256];
  int t = threadIdx.x;
  red[t] = cnt[blockIdx.x*256 + t];
  __syncthreads();
  for (int off=128; off>0; off>>=1){ if (t<off) red[t] += red[t+off]; __syncthreads(); }
  if (t==0) bsum[blockIdx.x] = red[0];
}

__global__ __launch_bounds__(1024) void scan1024_k(int* __restrict__ bsum){
  __shared__ int tmp[1024];
  int t = threadIdx.x;
  int v = bsum[t];
  tmp[t] = v; __syncthreads();
  for (int off=1; off<1024; off<<=1){
    int add = (t>=off) ? tmp[t-off] : 0;
    __syncthreads();
    tmp[t] += add;
    __syncthreads();
  }
  bsum[t] = tmp[t] - v;   // exclusive prefix
}

__global__ __launch_bounds__(256) void scanfinal_k(const int* __restrict__ cnt, const int* __restrict__ boff,
                                                   int* __restrict__ rowptr, int* __restrict__ fill){
  __shared__ int tmp[256];
  int t = threadIdx.x, gid = blockIdx.x*256 + t;
  int v = cnt[gid];
  tmp[t] = v; __syncthreads();
  for (int off=1; off<256; off<<=1){
    int add = (t>=off) ? tmp[t-off] : 0;
    __syncthreads();
    tmp[t] += add;
    __syncthreads();
  }
  int excl = boff[blockIdx.x] + tmp[t] - v;
  rowptr[gid] = excl; fill[gid] = excl;
  if (gid==0) rowptr[NN] = EE;
}

// multipass fill: pass p only scatters dst in [p*32768, (p+1)*32768) -> colv window
// stays resident in each XCD's 4MB L2, killing the 16x write amplification.
__global__ __launch_bounds__(256) void fill_k(const int* __restrict__ src, const int* __restrict__ dst,
                                              int* __restrict__ fill, int* __restrict__ colv, int pass){
  int e = blockIdx.x*256 + threadIdx.x;
  int d = dst[e];
  if ((d >> 15) == pass){
    int pos = atomicAdd(&fill[d], 1);
    colv[pos] = src[e];
  }
}

// ---------------- weight prep: transpose to [n][k] + bf16 ----------------
__global__ __launch_bounds__(256) void prepw_k(const float* __restrict__ W1, const float* __restrict__ W2,
    const float* __restrict__ W3, const float* __restrict__ Whw,
    unsigned short* __restrict__ W1t, unsigned short* __restrict__ W2t,
    unsigned short* __restrict__ W3t, unsigned short* __restrict__ Whwt)
{
  int b = blockIdx.x, t = threadIdx.x;
  const float* W = (b==0)?W1:(b==1)?W2:(b==2)?W3:Whw;
  unsigned short* Wt = (b==0)?W1t:(b==1)?W2t:(b==2)?W3t:Whwt;
  int ncols = (b==3)?64:128;
  for (int idx=t; idx<128*ncols; idx+=256){
    int k = idx/ncols, n = idx%ncols;
    Wt[n*128 + k] = f2bf(W[idx]);
  }
}

// ---------------- MFMA GEMM: C[Mx BN] = A[Mx128] @ W[128xBN] ----------------
// AMODE 0: A fp32 raw; AMODE 1: A bf16 + per-col affine + ReLU.
// Wt is pre-transposed bf16 [BN][128]. OUTBF: bf16 out else fp32. HASB: +bias.
template<int BN, int AMODE, int OUTBF, int HASB>
__global__ __launch_bounds__(256) void mgemm_k(
    const void* __restrict__ Ap, const float* __restrict__ scale, const float* __restrict__ shift,
    const unsigned short* __restrict__ Wt, const float* __restrict__ bias, void* __restrict__ Cp)
{
  constexpr int NT = BN/32;   // n-tiles per wave
  __shared__ __align__(16) char smem[(64+BN)*136*2];
  unsigned short (*Al)[136] = (unsigned short(*)[136])smem;
  unsigned short (*Wl)[136] = (unsigned short(*)[136])(smem + 64*136*2);
  const int tid = threadIdx.x;
  const int row0 = blockIdx.x*64;

  // stage A (64 rows x 128 cols, bf16 in LDS)
  if constexpr (AMODE==1){
    const unsigned short* A = (const unsigned short*)Ap;
    #pragma unroll
    for (int i=0;i<4;i++){
      int idx = tid + i*256;            // 1024 chunks of 8
      int r = idx>>4, c8 = (idx&15)*8;
      uint4 u = *(const uint4*)&A[(size_t)(row0+r)*128 + c8];
      float4 s0 = *(const float4*)&scale[c8];
      float4 s1 = *(const float4*)&scale[c8+4];
      float4 h0 = *(const float4*)&shift[c8];
      float4 h1 = *(const float4*)&shift[c8+4];
      uint4 o;
      o.x = packbf(fmaxf(fmaf(bflo(u.x),s0.x,h0.x),0.f), fmaxf(fmaf(bfhi(u.x),s0.y,h0.y),0.f));
      o.y = packbf(fmaxf(fmaf(bflo(u.y),s0.z,h0.z),0.f), fmaxf(fmaf(bfhi(u.y),s0.w,h0.w),0.f));
      o.z = packbf(fmaxf(fmaf(bflo(u.z),s1.x,h1.x),0.f), fmaxf(fmaf(bfhi(u.z),s1.y,h1.y),0.f));
      o.w = packbf(fmaxf(fmaf(bflo(u.w),s1.z,h1.z),0.f), fmaxf(fmaf(bfhi(u.w),s1.w,h1.w),0.f));
      *(uint4*)&Al[r][c8] = o;
    }
  } else {
    const float* A = (const float*)Ap;
    #pragma unroll
    for (int i=0;i<4;i++){
      int idx = tid + i*256;
      int r = idx>>4, c8 = (idx&15)*8;
      float4 a0 = *(const float4*)&A[(size_t)(row0+r)*128 + c8];
      float4 a1 = *(const float4*)&A[(size_t)(row0+r)*128 + c8 + 4];
      uint4 o;
      o.x = packbf(a0.x, a0.y); o.y = packbf(a0.z, a0.w);
      o.z = packbf(a1.x, a1.y); o.w = packbf(a1.z, a1.w);
      *(uint4*)&Al[r][c8] = o;
    }
  }
  // stage W
  #pragma unroll
  for (int i=0;i<BN*16/256;i++){
    int idx = tid + i*256;
    int r = idx>>4, c8 = (idx&15)*8;
    *(uint4*)&Wl[r][c8] = *(const uint4*)&Wt[r*128 + c8];
  }
  __syncthreads();

  const int wave = tid>>6, lane = tid&63;
  const int rH = wave>>1, cH = wave&1;
  const int lm = lane&15, lk = (lane>>4)*8;
  f32x4 acc[2][NT];
  #pragma unroll
  for (int m=0;m<2;m++)
    #pragma unroll
    for (int t=0;t<NT;t++){ acc[m][t].x=0.f; acc[m][t].y=0.f; acc[m][t].z=0.f; acc[m][t].w=0.f; }

  #pragma unroll
  for (int c=0;c<4;c++){
    int k0 = c*32 + lk;
    short8 a0 = *(const short8*)&Al[rH*32 + lm][k0];
    short8 a1 = *(const short8*)&Al[rH*32 + 16 + lm][k0];
    #pragma unroll
    for (int t=0;t<NT;t++){
      short8 b = *(const short8*)&Wl[cH*(BN/2) + t*16 + lm][k0];
      acc[0][t] = __builtin_amdgcn_mfma_f32_16x16x32_bf16(a0, b, acc[0][t], 0,0,0);
      acc[1][t] = __builtin_amdgcn_mfma_f32_16x16x32_bf16(a1, b, acc[1][t], 0,0,0);
    }
  }

  // epilogue: registers -> LDS (row-major fp32) -> coalesced global
  __syncthreads();
  float (*Cst)[BN+4] = (float(*)[BN+4])smem;
  #pragma unroll
  for (int t=0;t<NT;t++){
    int colb = cH*(BN/2) + t*16 + lm;
    float bv = HASB ? bias[colb] : 0.f;
    #pragma unroll
    for (int mt=0;mt<2;mt++){
      int rowb = rH*32 + mt*16 + (lane>>4)*4;
      #pragma unroll
      for (int r=0;r<4;r++)
        Cst[rowb+r][colb] = acc[mt][t][r] + bv;
    }
  }
  __syncthreads();
  constexpr int C4 = BN/4;
  if constexpr (OUTBF){
    unsigned short* C = (unsigned short*)Cp;
    #pragma unroll
    for (int i=0;i<64*C4/256;i++){
      int idx = tid + i*256;
      int r = idx / C4, c4 = idx % C4;
      float4 v = *(const float4*)&Cst[r][c4*4];
      uint2 p; p.x = packbf(v.x, v.y); p.y = packbf(v.z, v.w);
      *(uint2*)&C[(size_t)(row0+r)*BN + c4*4] = p;
    }
  } else {
    float* C = (float*)Cp;
    #pragma unroll
    for (int i=0;i<64*C4/256;i++){
      int idx = tid + i*256;
      int r = idx / C4, c4 = idx % C4;
      *(float4*)&C[(size_t)(row0+r)*BN + c4*4] = *(const float4*)&Cst[r][c4*4];
    }
  }
}

// ---------------- GCN aggregation: one wave per dst node ----------------
__global__ __launch_bounds__(256) void agg_k(const unsigned* __restrict__ xw, const int* __restrict__ rowptr,
    const int* __restrict__ colv, const float* __restrict__ dinv, const float* __restrict__ bias,
    unsigned* __restrict__ outb)
{
  int node = blockIdx.x*4 + (threadIdx.x>>6);
  int lane = threadIdx.x & 63;
  int beg = rowptr[node], end = rowptr[node+1];
  float dn = dinv[node];
  unsigned su = xw[(size_t)node*64 + lane];
  float a0 = bflo(su)*dn, a1 = bfhi(su)*dn;   // self-loop: xw[n]*dinv[n]
  for (int base=beg; base<end; base+=64){
    int n = end - base; if (n > 64) n = 64;
    int se = 0; float dv = 0.f;
    if (lane < n){ se = colv[base+lane]; dv = dinv[se]; }
    int j = 0;
    for (; j+2 <= n; j += 2){
      int   s0 = __shfl(se, j),   s1 = __shfl(se, j+1);
      float d0 = __shfl(dv, j),   d1 = __shfl(dv, j+1);
      unsigned u0 = xw[(size_t)s0*64 + lane];
      unsigned u1 = xw[(size_t)s1*64 + lane];
      a0 = fmaf(bflo(u0), d0, a0); a1 = fmaf(bfhi(u0), d0, a1);
      a0 = fmaf(bflo(u1), d1, a0); a1 = fmaf(bfhi(u1), d1, a1);
    }
    if (j < n){
      int s0 = __shfl(se, j); float d0 = __shfl(dv, j);
      unsigned u0 = xw[(size_t)s0*64 + lane];
      a0 = fmaf(bflo(u0), d0, a0); a1 = fmaf(bfhi(u0), d0, a1);
    }
  }
  int c = lane*2;
  a0 = fmaf(a0, dn, bias[c]);
  a1 = fmaf(a1, dn, bias[c+1]);
  outb[(size_t)node*64 + lane] = packbf(a0, a1);
}

// ---------------- BN stats (sum, sumsq per column) ----------------
__global__ __launch_bounds__(256) void stats_k(const unsigned short* __restrict__ a,
                                               float* __restrict__ gsum, float* __restrict__ gss)
{
  int t = threadIdx.x;
  int c = t & 127, h = t >> 7;
  size_t r0 = (size_t)blockIdx.x * 256;
  float s = 0.f, ss = 0.f;
  for (int r = h; r < 256; r += 2){
    float v = bfs(a[(r0 + r)*128 + c]);
    s += v; ss = fmaf(v, v, ss);
  }
  __shared__ float red[256];
  red[t] = s; __syncthreads();
  if (t < 128) atomicAdd(&gsum[c], red[t] + red[t+128]);
  __syncthreads();
  red[t] = ss; __syncthreads();
  if (t < 128) atomicAdd(&gss[c], red[t] + red[t+128]);
}

__global__ void fin_k(const float* __restrict__ gsum, const float* __restrict__ gss,
                      const float* __restrict__ g, const float* __restrict__ be,
                      float* __restrict__ scale, float* __restrict__ shift)
{
  int c = threadIdx.x;
  float mean = gsum[c] * (1.0f/NN);
  float var  = gss[c]  * (1.0f/NN) - mean*mean;
  float rs = rsqrtf(var + 1e-5f);
  float sc = g[c]*rs;
  scale[c] = sc;
  shift[c] = be[c] - mean*sc;
}

// ---------------- phi = h1@phi1_w + phi1_b + h2@phi2_w ----------------
__global__ __launch_bounds__(256) void phi_k(const unsigned* __restrict__ a1, const float* __restrict__ sc1, const float* __restrict__ sh1,
    const unsigned* __restrict__ a2, const float* __restrict__ sc2, const float* __restrict__ sh2,
    const float* __restrict__ p1w, const float* __restrict__ p1b, const float* __restrict__ p2w,
    float* __restrict__ phi)
{
  int node = blockIdx.x*4 + (threadIdx.x>>6);
  int lane = threadIdx.x & 63;
  int c = lane*2;
  unsigned u1 = a1[(size_t)node*64+lane], u2 = a2[(size_t)node*64+lane];
  float h10 = fmaxf(fmaf(bflo(u1), sc1[c],   sh1[c]),   0.f);
  float h11 = fmaxf(fmaf(bfhi(u1), sc1[c+1], sh1[c+1]), 0.f);
  float h20 = fmaxf(fmaf(bflo(u2), sc2[c],   sh2[c]),   0.f);
  float h21 = fmaxf(fmaf(bfhi(u2), sc2[c+1], sh2[c+1]), 0.f);
  float acc = h10*p1w[c] + h11*p1w[c+1] + h20*p2w[c] + h21*p2w[c+1];
  #pragma unroll
  for (int off=32; off>0; off>>=1) acc += __shfl_xor(acc, off);
  if (lane==0) phi[node] = acc + p1b[0];
}

// ---------------- per-graph softmax + h_graph ----------------
__global__ __launch_bounds__(256) void attn_k(const float* __restrict__ phi, const unsigned short* __restrict__ a3,
    const float* __restrict__ sc3, const float* __restrict__ sh3, float* __restrict__ hgraph)
{
  int b = blockIdx.x, t = threadIdx.x;
  __shared__ float at[1024];
  __shared__ float red[256];
  const float* ph = phi + (size_t)b*1024;
  float m = -1e30f;
  for (int i=t;i<1024;i+=256) m = fmaxf(m, ph[i]);
  red[t] = m; __syncthreads();
  for (int off=128; off>0; off>>=1){ if (t<off) red[t] = fmaxf(red[t], red[t+off]); __syncthreads(); }
  m = red[0]; __syncthreads();
  float s = 0.f;
  for (int i=t;i<1024;i+=256){ float e = expf(ph[i]-m); at[i] = e; s += e; }
  red[t] = s; __syncthreads();
  for (int off=128; off>0; off>>=1){ if (t<off) red[t] += red[t+off]; __syncthreads(); }
  float inv = 1.0f/red[0];
  __syncthreads();
  int c = t & 127, h = t >> 7;
  float acc = 0.f;
  const unsigned short* base = a3 + (size_t)b*1024*128;
  float sc = sc3[c], sh = sh3[c];
  for (int p=h; p<1024; p+=2){
    float v = bfs(base[(size_t)p*128 + c]);
    float hv = fmaxf(fmaf(v, sc, sh), 0.f);
    acc = fmaf(hv, at[p], acc);
  }
  red[t] = acc; __syncthreads();
  if (t < 128) hgraph[(size_t)b*128 + t] = (red[t] + red[t+128]) * inv;
}

// ---------------- graph latent head ----------------
__global__ __launch_bounds__(64) void za_k(const float* __restrict__ hg,
   const float* __restrict__ muw, const float* __restrict__ mub,
   const float* __restrict__ lvw, const float* __restrict__ lvb,
   const float* __restrict__ epsA, float* __restrict__ out)
{
  int b = blockIdx.x, j = threadIdx.x;
  __shared__ float h[128];
  h[j] = hg[(size_t)b*128 + j]; h[j+64] = hg[(size_t)b*128 + 64 + j];
  __syncthreads();
  float mu = mub[j], lv = lvb[j];
  #pragma unroll 8
  for (int c=0;c<128;c++){
    mu = fmaf(h[c], muw[c*64+j], mu);
    lv = fmaf(h[c], lvw[c*64+j], lv);
  }
  float z = mu + epsA[(size_t)b*64+j]*expf(0.5f*lv);
  size_t o = (size_t)b*64 + j;
  out[OFF_ZA  + o] = z;
  out[OFF_MUA + o] = mu;
  out[OFF_LVA + o] = lv;
}

// ---------------- zt: s += z_A[b] @ WA[p], one block per node position p ----------------
__global__ __launch_bounds__(256) void zt_k(const float* __restrict__ zA, const float* __restrict__ WA,
                                            float* __restrict__ s)
{
  __shared__ float wa[4096];
  int p = blockIdx.x, t = threadIdx.x;
  #pragma unroll
  for (int i=0;i<16;i++){ int idx = t + i*256; wa[idx] = WA[(size_t)p*4096 + idx]; }
  __syncthreads();
  int f = t & 63, bg = t >> 6;
  for (int b = bg; b < 256; b += 4){
    const float* za = zA + (size_t)b*64;
    float acc = 0.f;
    #pragma unroll 8
    for (int g=0; g<64; g++) acc = fmaf(za[g], wa[g*64+f], acc);
    size_t idx = ((size_t)b*1024 + p)*64 + f;
    s[idx] += acc;
  }
}

// ---------------- node head: mu_i, logvar_i, z_i ----------------
__global__ __launch_bounds__(256) void out_k(const float* __restrict__ s,
    const float* __restrict__ muw, const float* __restrict__ mub,
    const float* __restrict__ lvw, const float* __restrict__ lvb,
    const float* __restrict__ eps, float* __restrict__ out)
{
  __shared__ float wmu[4096];
  __shared__ float wlv[4096];
  __shared__ float sl[4096];
  int t = threadIdx.x;
  size_t base = (size_t)blockIdx.x * 64;
  #pragma unroll
  for (int i=0;i<16;i++){
    int idx = t + i*256;
    wmu[idx] = muw[idx]; wlv[idx] = lvw[idx];
    sl[idx] = s[base*64 + idx];
  }
  __syncthreads();
  int f = t & 63, ng = t >> 6;
  float mb = mub[f], lb = lvb[f];
  for (int nl = ng; nl < 64; nl += 4){
    size_t node = base + nl;
    float mu = mb, lv = lb;
    const float* srow = &sl[nl*64];
    #pragma unroll 16
    for (int k=0;k<64;k++){
      float sv = srow[k];
      mu = fmaf(sv, wmu[k*64+f], mu);
      lv = fmaf(sv, wlv[k*64+f], lv);
    }
    float e = eps[node*64 + f];
    float zi = mu + e*expf(0.5f*lv);
    size_t o = node*64 + f;
    out[o] = zi;
    out[OFF_MUI + o] = mu;
    out[OFF_LVI + o] = lv;
  }
}

extern "C" void kernel_launch(void* const* d_in, const int* in_sizes, int n_in,
                              void* d_out, int out_size, void* d_ws, size_t ws_size,
                              hipStream_t stream)
{
  (void)in_sizes; (void)n_in; (void)out_size; (void)ws_size;
  const float* x    = (const float*)d_in[0];
  const float* epsA = (const float*)d_in[1];
  const float* epsI = (const float*)d_in[2];
  const float* W1 = (const float*)d_in[3];
  const float* b1 = (const float*)d_in[4];
  const float* W2 = (const float*)d_in[5];
  const float* b2 = (const float*)d_in[6];
  const float* W3 = (const float*)d_in[7];
  const float* b3 = (const float*)d_in[8];
  const float* g1 = (const float*)d_in[9];
  const float* be1= (const float*)d_in[10];
  const float* g2 = (const float*)d_in[11];
  const float* be2= (const float*)d_in[12];
  const float* g3 = (const float*)d_in[13];
  const float* be3= (const float*)d_in[14];
  const float* p1w= (const float*)d_in[15];
  const float* p1b= (const float*)d_in[16];
  const float* p2w= (const float*)d_in[17];
  const float* muAw=(const float*)d_in[18];
  const float* muAb=(const float*)d_in[19];
  const float* lvAw=(const float*)d_in[20];
  const float* lvAb=(const float*)d_in[21];
  const float* Whw= (const float*)d_in[22];
  const float* Whb= (const float*)d_in[23];
  const float* WAp= (const float*)d_in[24];
  const float* muiw=(const float*)d_in[25];
  const float* muib=(const float*)d_in[26];
  const float* lviw=(const float*)d_in[27];
  const float* lvib=(const float*)d_in[28];
  const int* edge = (const int*)d_in[29];
  const int* srcp = edge;
  const int* dstp = edge + EE;

  char* w = (char*)d_ws;
  size_t o = 0;
  auto alloc = [&](size_t bytes)->void*{ void* p = w + o; o += (bytes + 255) & ~(size_t)255; return p; };
  void* bufX = alloc((size_t)NN*128*2);   // bf16 xw; later reused as fp32 s[N][64]
  void* buf1 = alloc((size_t)NN*128*2);   // agg1 (bf16), later agg3
  void* buf2 = alloc((size_t)NN*128*2);   // agg2 (bf16)
  int*   colv  = (int*)alloc((size_t)EE*4);
  int*   cnt   = (int*)alloc((size_t)NN*4);
  int*   rowptr= (int*)alloc((size_t)(NN+1)*4);
  int*   fill  = (int*)alloc((size_t)NN*4);
  float* dinv  = (float*)alloc((size_t)NN*4);
  float* phi   = (float*)alloc((size_t)NN*4);
  int*   bsum  = (int*)alloc(1024*4);
  float* stats = (float*)alloc(768*4);
  float* aff   = (float*)alloc(768*4);
  float* hgraph= (float*)alloc((size_t)BGR*128*4);
  unsigned short* W1t = (unsigned short*)alloc(128*128*2);
  unsigned short* W2t = (unsigned short*)alloc(128*128*2);
  unsigned short* W3t = (unsigned short*)alloc(128*128*2);
  unsigned short* Whwt= (unsigned short*)alloc(64*128*2);
  float* sc1 = aff, *sh1 = aff+128, *sc2 = aff+256, *sh2 = aff+384, *sc3 = aff+512, *sh3 = aff+640;

  hipMemsetAsync(cnt, 0, (size_t)NN*4, stream);
  hipMemsetAsync(stats, 0, 768*4, stream);

  // weight prep + CSR build
  prepw_k<<<4,256,0,stream>>>(W1, W2, W3, Whw, W1t, W2t, W3t, Whwt);
  count_k<<<EE/256,256,0,stream>>>(dstp, cnt);
  dinv_k<<<NN/256,256,0,stream>>>(cnt, dinv);
  reduce256_k<<<NN/256,256,0,stream>>>(cnt, bsum);
  scan1024_k<<<1,1024,0,stream>>>(bsum);
  scanfinal_k<<<NN/256,256,0,stream>>>(cnt, bsum, rowptr, fill);
  for (int p=0;p<8;p++)
    fill_k<<<EE/256,256,0,stream>>>(srcp, dstp, fill, colv, p);

  float* out = (float*)d_out;

  // layer 1
  mgemm_k<128,0,1,0><<<NN/64,256,0,stream>>>(x, nullptr, nullptr, W1t, nullptr, bufX);
  agg_k<<<NN/4,256,0,stream>>>((const unsigned*)bufX, rowptr, colv, dinv, b1, (unsigned*)buf1);
  stats_k<<<NN/256,256,0,stream>>>((const unsigned short*)buf1, stats+0, stats+128);
  fin_k<<<1,128,0,stream>>>(stats+0, stats+128, g1, be1, sc1, sh1);
  // layer 2
  mgemm_k<128,1,1,0><<<NN/64,256,0,stream>>>(buf1, sc1, sh1, W2t, nullptr, bufX);
  agg_k<<<NN/4,256,0,stream>>>((const unsigned*)bufX, rowptr, colv, dinv, b2, (unsigned*)buf2);
  stats_k<<<NN/256,256,0,stream>>>((const unsigned short*)buf2, stats+256, stats+384);
  fin_k<<<1,128,0,stream>>>(stats+256, stats+384, g2, be2, sc2, sh2);
  // phi (needs h1,h2) before buf1 is reused
  phi_k<<<NN/4,256,0,stream>>>((const unsigned*)buf1, sc1, sh1, (const unsigned*)buf2, sc2, sh2,
                               p1w, p1b, p2w, phi);
  // layer 3
  mgemm_k<128,1,1,0><<<NN/64,256,0,stream>>>(buf2, sc2, sh2, W3t, nullptr, bufX);
  agg_k<<<NN/4,256,0,stream>>>((const unsigned*)bufX, rowptr, colv, dinv, b3, (unsigned*)buf1);
  stats_k<<<NN/256,256,0,stream>>>((const unsigned short*)buf1, stats+512, stats+640);
  fin_k<<<1,128,0,stream>>>(stats+512, stats+640, g3, be3, sc3, sh3);
  // attention pooling + graph latent
  attn_k<<<BGR,256,0,stream>>>(phi, (const unsigned short*)buf1, sc3, sh3, hgraph);
  za_k<<<BGR,64,0,stream>>>(hgraph, muAw, muAb, lvAw, lvAb, epsA, out);
  // node head: s = h3 @ Wh_w + Wh_b  (fp32, into bufX)
  mgemm_k<64,1,0,1><<<NN/64,256,0,stream>>>(buf1, sc3, sh3, Whwt, Whb, bufX);
  zt_k<<<NPG,256,0,stream>>>(out + OFF_ZA, WAp, (float*)bufX);
  out_k<<<NN/64,256,0,stream>>>((const float*)bufX, muiw, muib, lviw, lvib, epsI, out);
}